// Round 3
// baseline (256.474 us; speedup 1.0000x reference)
//
#include <hip/hip_runtime.h>
#include <math.h>

#define E_LEN 512
#define C_CLS 14
#define BATCH 8192
#define S_PER_BLOCK 4
#define NSLOTS 256
#define SCR_STRIDE 68  // words per class row: 8 partials x 8 m + pad (16B-aligned)

typedef float v2f __attribute__((ext_vector_type(2)));
typedef float v4f __attribute__((ext_vector_type(4)));

// packed fp32 FMA with op_sel broadcast of w.lo / w.hi (CDNA VOP3P)
#define PK_FMA_LO(acc, u, wv) \
  asm("v_pk_fma_f32 %0, %1, %2, %0 op_sel_hi:[1,0,1]" : "+v"(acc) : "v"(u), "v"(wv))
#define PK_FMA_HI(acc, u, wv) \
  asm("v_pk_fma_f32 %0, %1, %2, %0 op_sel:[0,1,0]" : "+v"(acc) : "v"(u), "v"(wv))
#define PK_MUL_LO(d, u, wv) \
  asm("v_pk_mul_f32 %0, %1, %2 op_sel_hi:[1,0]" : "=v"(d) : "v"(u), "v"(wv))
#define PK_MUL_HI(d, u, wv) \
  asm("v_pk_mul_f32 %0, %1, %2 op_sel:[0,1]" : "=v"(d) : "v"(u), "v"(wv))

// raw barrier: drain LDS only (keeps global prefetch loads in flight,
// unlike __syncthreads which drains vmcnt(0))
#define BAR() asm volatile("s_waitcnt lgkmcnt(0)\ns_barrier" ::: "memory")

// ---- DPP helpers (VALU pipe) ----
template<int CTRL>
__device__ __forceinline__ float dpp_mov_f(float v) {
  return __int_as_float(__builtin_amdgcn_update_dpp(
      0, __float_as_int(v), CTRL, 0xF, 0xF, false));
}
__device__ __forceinline__ float sum16(float v) {  // full row16 sum (ror 8,4,2,1)
  v += dpp_mov_f<0x128>(v);
  v += dpp_mov_f<0x124>(v);
  v += dpp_mov_f<0x122>(v);
  v += dpp_mov_f<0x121>(v);
  return v;
}
__device__ __forceinline__ float wsum64(float v) {  // lane63 = full wave sum
  v = sum16(v);
  v += dpp_mov_f<0x142>(v);  // row_bcast15
  v += dpp_mov_f<0x143>(v);  // row_bcast31
  return v;
}
__device__ __forceinline__ float rl63(float v) {
  return __int_as_float(__builtin_amdgcn_readlane(__float_as_int(v), 63));
}
__device__ __forceinline__ float max8(float v) {  // max over aligned groups of 8
  v = fmaxf(v, dpp_mov_f<0xB1>(v));
  v = fmaxf(v, dpp_mov_f<0x4E>(v));
  v = fmaxf(v, dpp_mov_f<0x141>(v));
  return v;
}
__device__ __forceinline__ float softplus_f(float v) {
  return fmaxf(v, 0.f) + __logf(1.f + __expf(-fabsf(v)));
}

// ---- prep (1 block): zero 256 slots, Gram G = w^T w into ws[256..451] ----
__global__ void MID_LOSS_prep(const float* __restrict__ w,
                              float* __restrict__ wsf) {
  __shared__ float wl[E_LEN * C_CLS];
  const int tid = threadIdx.x;
#pragma unroll
  for (int i = 0; i < 7; ++i)
    ((float4*)wl)[tid + i * 256] = ((const float4*)w)[tid + i * 256];
  wsf[tid] = 0.f;  // slots
  __syncthreads();
  if (tid < 196) {
    const int p = tid / 14, n = tid - p * 14;
    float g = 0.f;
    for (int e = 0; e < E_LEN; ++e)
      g = fmaf(wl[e * 14 + p], wl[e * 14 + n], g);
    wsf[NSLOTS + tid] = g;
  }
}

// ---- main: 1 block = 4 samples; 4 waves = (e-half, m-half); x read ONCE ----
__global__ __launch_bounds__(256, 4)
void MID_LOSS_main(const float* __restrict__ x, const int* __restrict__ y,
                   const float* __restrict__ w, const float* __restrict__ wsf,
                   float* __restrict__ slots) {
  __shared__ alignas(16) float wp_s[7 * 1024];       // [c-pair][e][2] (28 KB)
  __shared__ alignas(16) float scr[14 * SCR_STRIDE]; // [c][8 part][8 m] (3.7 KB)
  __shared__ alignas(8)  float var_s[E_LEN * 2];     // per-e (s1,s2) of mh=1 (4 KB)
  __shared__ float G_s[196];
  __shared__ float P4_s[S_PER_BLOCK * C_CLS];
  __shared__ float dot_s[C_CLS];
  __shared__ float l1_scr[8];
  __shared__ float npos_s[S_PER_BLOCK];
  __shared__ float w2sum_s[S_PER_BLOCK];

  const int tid = threadIdx.x;
  const int lane = tid & 63;
  const int wid = tid >> 6;
  const int mh = wid & 1;   // m-half: 0 -> m0..3, 1 -> m4..7
  const int eh = wid >> 1;  // e-half
  const int ebase = eh * 256 + lane;
  const int b0 = blockIdx.x * S_PER_BLOCK;

  // ---- issue sample-0 x loads first (prefetch) ----
  alignas(16) v2f U[2][4][2];  // ping-pong [cur][j][m-pair]
  {
    const float* xr = x + (size_t)b0 * (E_LEN * 8);
#pragma unroll
    for (int j = 0; j < 4; ++j)
      *(v4f*)&U[0][j][0] = *(const v4f*)(xr + (ebase + j * 64) * 8 + mh * 4);
  }

  // ---- prologue: repack w into LDS, stage G, P, per-sample npos/sumW2 ----
#pragma unroll
  for (int i = 0; i < 7; ++i) {
    const int idx = tid + i * 256;
    const v4f v = ((const v4f*)w)[idx];
#pragma unroll
    for (int k = 0; k < 4; ++k) {
      const int f = idx * 4 + k;
      const int e = f / 14;
      const int c = f - e * 14;
      wp_s[(c >> 1) * 1024 + e * 2 + (c & 1)] = v[k];
    }
  }
  if (tid < 196) G_s[tid] = wsf[NSLOTS + tid];
  if (tid < S_PER_BLOCK * C_CLS)
    P4_s[tid] = (y[b0 * C_CLS + tid] == 1) ? 1.f : 0.f;
  BAR();
  if (tid < S_PER_BLOCK) {
    float np = 0.f;
    for (int c = 0; c < C_CLS; ++c) np += P4_s[tid * C_CLS + c];
    npos_s[tid] = np;
  } else if (tid < 2 * S_PER_BLOCK) {
    const int s = tid - S_PER_BLOCK;
    float sw = 0.f;
    for (int c = 0; c < C_CLS; ++c)
      sw = fmaf(P4_s[s * C_CLS + c], G_s[c * 15], sw);
    w2sum_s[s] = sw;
  }
  BAR();

  float block_loss = 0.f;

#pragma unroll
  for (int s = 0; s < S_PER_BLOCK; ++s) {
    const int cur = s & 1, nxt = cur ^ 1;

    // ---- phase 1: variance partials over this m-half ----
    float vs1[4], vs2[4];
#pragma unroll
    for (int j = 0; j < 4; ++j) {
      const v2f t = U[cur][j][0] + U[cur][j][1];
      vs1[j] = t.x + t.y;
      v2f q = U[cur][j][0] * U[cur][j][0];
      q += U[cur][j][1] * U[cur][j][1];
      vs2[j] = q.x + q.y;
    }
    if (mh == 1) {
#pragma unroll
      for (int j = 0; j < 4; ++j) {
        v2f o;
        o.x = vs1[j];
        o.y = vs2[j];
        *(v2f*)(var_s + 2 * (ebase + j * 64)) = o;
      }
    }

    // ---- phase 1: packed-FMA dot accumulation (j=0 peeled as init) ----
    alignas(16) v2f acc[14][2];
#pragma unroll
    for (int j = 0; j < 4; ++j) {
      const int e = ebase + j * 64;
      const float* wb = wp_s + e * 2;
#pragma unroll
      for (int cp = 0; cp < 7; ++cp) {
        const v2f wv = *(const v2f*)(wb + cp * 1024);
        if (j == 0) {
          PK_MUL_LO(acc[2 * cp][0], U[cur][0][0], wv);
          PK_MUL_LO(acc[2 * cp][1], U[cur][0][1], wv);
          PK_MUL_HI(acc[2 * cp + 1][0], U[cur][0][0], wv);
          PK_MUL_HI(acc[2 * cp + 1][1], U[cur][0][1], wv);
        } else {
          PK_FMA_LO(acc[2 * cp][0], U[cur][j][0], wv);
          PK_FMA_LO(acc[2 * cp][1], U[cur][j][1], wv);
          PK_FMA_HI(acc[2 * cp + 1][0], U[cur][j][0], wv);
          PK_FMA_HI(acc[2 * cp + 1][1], U[cur][j][1], wv);
        }
      }
    }

    // ---- prefetch next sample's x (stays in flight across raw barriers) ----
    if (s < S_PER_BLOCK - 1) {
      const float* xn = x + (size_t)(b0 + s + 1) * (E_LEN * 8);
#pragma unroll
      for (int j = 0; j < 4; ++j)
        *(v4f*)&U[nxt][j][0] = *(const v4f*)(xn + (ebase + j * 64) * 8 + mh * 4);
    }

    // ---- full in-wave reduction (row16 sums, in place) ----
#pragma unroll
    for (int c = 0; c < 14; ++c) {
      acc[c][0].x = sum16(acc[c][0].x);
      acc[c][0].y = sum16(acc[c][0].y);
      acc[c][1].x = sum16(acc[c][1].x);
      acc[c][1].y = sum16(acc[c][1].y);
    }
    // one writer lane per row16 -> conflict-free b128 stores, imm offsets
    if ((lane & 15) == 0) {
      float* sp = scr + (eh * 4 + (lane >> 4)) * 8 + mh * 4;
#pragma unroll
      for (int c = 0; c < 14; ++c)
        *(float4*)(sp + c * SCR_STRIDE) = *(float4*)&acc[c][0];
    }
    BAR();  // B

    // ---- phase 2a (mh=1): finish dot sums, max over m ----
    if (mh == 1) {
      const int r = eh * 64 + lane;
      const int craw = r >> 3;
      const int c = (craw > 13) ? 13 : craw;
      const int m = r & 7;
      const float* sp = scr + c * SCR_STRIDE + m;
      float dv = sp[0] + sp[8] + sp[16] + sp[24] + sp[32] + sp[40] + sp[48] + sp[56];
      dv = max8(dv);
      if ((r & 7) == 0 && craw < 14) dot_s[c] = dv;
    } else {
      // ---- phase 2b (mh=0): finalize per-e variance -> l1 ----
      float l1 = 0.f;
#pragma unroll
      for (int j = 0; j < 4; ++j) {
        const v2f o = *(const v2f*)(var_s + 2 * (ebase + j * 64));
        const float s1 = vs1[j] + o.x;
        const float s2 = vs2[j] + o.y;
        const float sig = (s2 - s1 * s1 * 0.125f) * (1.f / 7.f);  // ddof=1
        l1 += fabsf(sig);
      }
      l1 = sum16(l1);
      if ((lane & 15) == 0) l1_scr[eh * 4 + (lane >> 4)] = l1;
    }
    BAR();  // C

    // ---- phase 3+4: wave 0 only (no extra barrier; in-wave ordering) ----
    if (wid == 0) {
      const float* Pv = P4_s + s * C_CLS;
      float Sc = 0.f, Gc = 0.f, Lc = 0.f;
#pragma unroll
      for (int k = 0; k < 4; ++k) {
        const int tt = lane + k * 64;
        if (tt < 196) {
          const int p = (tt * 2341) >> 15;  // tt/14, exact for tt<196
          const int n = tt - p * 14;
          const float Pp = Pv[p], Pn = Pv[n];
          Sc += Pp * (1.f - Pn) * softplus_f(dot_s[n] - dot_s[p]);
          Gc = fmaf(Pp * Pn, G_s[tt], Gc);
        }
      }
      if (lane < 8) Lc = l1_scr[lane];
      Sc = wsum64(Sc);
      Gc = wsum64(Gc);
      Lc = wsum64(Lc);
      const float S = rl63(Sc), sumG = rl63(Gc), l1e = rl63(Lc);
      const float npos = npos_s[s];
      const float base = S / npos;  // nneg>=1 guaranteed by setup (y[:,-1]=0)
      const float tv =
          (npos > 1.5f) ? (w2sum_s[s] - sumG / npos) / (npos - 1.f) : 0.f;
      // loss = 2*((1-beta)*(1+tv)*base + beta*l1), beta=0.3
      block_loss += 1.4f * (1.f + tv) * base + 0.6f * l1e;
    }
  }
  if (tid == 0) atomicAdd(&slots[blockIdx.x & (NSLOTS - 1)], block_loss);
}

// ---- finalize (1 wave): sum the 256 slots -> out[0] ----
__global__ void MID_LOSS_fin(const float* __restrict__ wsf,
                             float* __restrict__ out) {
  const int tid = threadIdx.x;  // 64 threads
  float s = wsf[tid] + wsf[tid + 64] + wsf[tid + 128] + wsf[tid + 192];
  s = wsum64(s);
  if (tid == 63) out[0] = s * (1.f / (float)BATCH);
}

extern "C" void kernel_launch(void* const* d_in, const int* in_sizes, int n_in,
                              void* d_out, int out_size, void* d_ws, size_t ws_size,
                              hipStream_t stream) {
  const float* x = (const float*)d_in[0];
  const int* y = (const int*)d_in[1];
  const float* w = (const float*)d_in[2];
  float* out = (float*)d_out;
  float* wsf = (float*)d_ws;

  MID_LOSS_prep<<<1, 256, 0, stream>>>(w, wsf);
  MID_LOSS_main<<<BATCH / S_PER_BLOCK, 256, 0, stream>>>(x, y, w, wsf, wsf);
  MID_LOSS_fin<<<1, 64, 0, stream>>>(wsf, out);
}

// Round 4
// 216.796 us; speedup vs baseline: 1.1830x; 1.1830x over previous
//
#include <hip/hip_runtime.h>
#include <math.h>

#define E_LEN 512
#define C_CLS 14
#define BATCH 8192
#define NSLOTS 256
#define WS_G 256    // Gram offset in ws (floats)
#define WS_WB 464   // packed bf16 w offset in ws (dwords)
#define WB_ROW 260  // dwords per wB row (512 bf16 + 8 pad -> 2-way-free LDS reads)

typedef float v4f __attribute__((ext_vector_type(4)));
typedef short s8v __attribute__((ext_vector_type(8)));  // 8 bf16 (4 VGPRs)
union APk { int i[4]; s8v s; };

// f32 pair -> packed bf16 (RNE), gfx950 VOP3
#define CVT_PK_BF16(d, a, b) \
  asm("v_cvt_pk_bf16_f32 %0, %1, %2" : "=v"(d) : "v"(a), "v"(b))

// ---- cross-lane helpers ----
template<int CTRL>
__device__ __forceinline__ float dpp_mov_f(float v) {
  return __int_as_float(__builtin_amdgcn_update_dpp(
      0, __float_as_int(v), CTRL, 0xF, 0xF, false));
}
__device__ __forceinline__ float sum16(float v) {  // row16 sum (ror 8,4,2,1)
  v += dpp_mov_f<0x128>(v);
  v += dpp_mov_f<0x124>(v);
  v += dpp_mov_f<0x122>(v);
  v += dpp_mov_f<0x121>(v);
  return v;
}
// lane31 = sum(lanes 0..31), lane63 = sum(lanes 32..63)
__device__ __forceinline__ float hsum32(float v) {
  v = sum16(v);
  v += dpp_mov_f<0x142>(v);  // row_bcast15
  return v;
}
__device__ __forceinline__ float wsum64(float v) {
  v = sum16(v);
  v += dpp_mov_f<0x142>(v);
  v += dpp_mov_f<0x143>(v);
  return v;
}
template<int PAT>
__device__ __forceinline__ float swz_f(float v) {  // 32-lane-group swizzle
  return __int_as_float(__builtin_amdgcn_ds_swizzle(__float_as_int(v), PAT));
}
__device__ __forceinline__ float shfl_x32(float v) {  // cross-half via bpermute
  return __shfl_xor(v, 32, 64);
}
__device__ __forceinline__ float softplus_f(float v) {
  return fmaxf(v, 0.f) + __logf(1.f + __expf(-fabsf(v)));
}

// ---- prep (1 block): zero slots, Gram G=w^T w (fp32), pack w -> bf16 rows ----
__global__ void MID_LOSS_prep(const float* __restrict__ w,
                              float* __restrict__ wsf) {
  __shared__ float wl[E_LEN * C_CLS];
  const int tid = threadIdx.x;
#pragma unroll
  for (int i = 0; i < 7; ++i)
    ((float4*)wl)[tid + i * 256] = ((const float4*)w)[tid + i * 256];
  wsf[tid] = 0.f;  // slots
  __syncthreads();
  if (tid < 196) {
    const int p = tid / 14, n = tid - p * 14;
    float g = 0.f;
    for (int e = 0; e < E_LEN; ++e)
      g = fmaf(wl[e * 14 + p], wl[e * 14 + n], g);
    wsf[WS_G + tid] = g;
  }
  // wB[c][e] bf16, c padded to 16 (zeros), row stride WB_ROW dwords
  unsigned int* wsu = (unsigned int*)wsf;
  for (int i = tid; i < 4096; i += 256) {
    const int c = i >> 8;        // 0..15
    const int ep = i & 255;      // e-pair
    const int e = ep * 2;
    const float v0 = (c < 14) ? wl[e * 14 + c] : 0.f;
    const float v1 = (c < 14) ? wl[(e + 1) * 14 + c] : 0.f;
    int d;
    CVT_PK_BF16(d, v0, v1);
    wsu[WS_WB + c * WB_ROW + ep] = (unsigned int)d;
  }
}

// ---- main: 1 block = 8 samples; each wave owns 2 samples, barrier-free loop --
__global__ __launch_bounds__(256, 4)
void MID_LOSS_main(const float* __restrict__ x, const int* __restrict__ y,
                   const float* __restrict__ wsf, float* __restrict__ slots) {
  __shared__ unsigned int wB_l[16 * WB_ROW];  // 16.6 KB bf16 w
  __shared__ float G_l[196];
  __shared__ float dots_l[4][2][16];
  __shared__ float P_l[4][2][16];

  const int tid = threadIdx.x;
  const int lane = tid & 63;
  const int wid = tid >> 6;
  const unsigned int* wsu = (const unsigned int*)wsf;

  // stage packed w + Gram once per block
  for (int i = tid; i < 16 * WB_ROW; i += 256) wB_l[i] = wsu[WS_WB + i];
  if (tid < 196) G_l[tid] = wsf[WS_G + tid];
  __syncthreads();

  // per-lane geometry: A-frag row = lane&15 -> (sample, m); kgroup = lane>>4
  const int row = lane & 15;
  const int kg = lane >> 4;
  const int b0 = blockIdx.x * 8 + wid * 2;  // this wave's 2 samples
  const int b = b0 + (row >> 3);
  const int m = row & 7;
  const float* xp = x + (size_t)b * (E_LEN * 8) + kg * 64 + m;

  // ---- K-loop: 16 chunks of 32 e; dot-MFMA + Gram-MFMA + fp32 sum(u^2) ----
  v4f acc = {0.f, 0.f, 0.f, 0.f};   // dot C-tile
  v4f acc2 = {0.f, 0.f, 0.f, 0.f};  // Gram C-tile (A*A^T)
  float q = 0.f;                    // fp32 sum of u^2 (this lane's row slice)
#pragma unroll
  for (int ch = 0; ch < 16; ++ch) {
    const float* xc = xp + ch * 256;
    float u[8];
#pragma unroll
    for (int j = 0; j < 8; ++j) u[j] = xc[j * 8];
#pragma unroll
    for (int j = 0; j < 8; ++j) q = fmaf(u[j], u[j], q);
    APk a;
#pragma unroll
    for (int jj = 0; jj < 4; ++jj) CVT_PK_BF16(a.i[jj], u[2 * jj], u[2 * jj + 1]);
    const s8v bfrag =
        *(const s8v*)(wB_l + (lane & 15) * WB_ROW + ch * 16 + kg * 4);
    acc = __builtin_amdgcn_mfma_f32_16x16x32_bf16(a.s, bfrag, acc, 0, 0, 0);
    acc2 = __builtin_amdgcn_mfma_f32_16x16x32_bf16(a.s, a.s, acc2, 0, 0, 0);
  }

  // ---- stage P mask for the wave's 2 samples (same-wave, no barrier) ----
  if (lane < 28) {
    const int s = (lane >= 14) ? 1 : 0;
    P_l[wid][s][lane - s * 14] = (y[b0 * 14 + lane] == 1) ? 1.f : 0.f;
  }

  // ---- dot tail: max over m ----
  // C layout: col=lane&15 (class), row=(lane>>4)*4+reg
  float dmax = fmaxf(fmaxf(acc[0], acc[1]), fmaxf(acc[2], acc[3]));
  dmax = fmaxf(dmax, swz_f<0x401F>(dmax));  // xor16: combine kg pairs
  // lanes 0-31 hold dot_b0[c], lanes 32-63 hold dot_b1[c]
  if ((lane & 16) == 0 && (lane & 15) < 14)
    dots_l[wid][lane >> 5][lane & 15] = dmax;

  // ---- Gram tail: S2_b = sum of b's 8x8 block (for l1) ----
  const float loc2 = acc2[0] + acc2[1] + acc2[2] + acc2[3];
  const bool validb = (((lane & 15) < 8) == (lane < 32));
  float s2v = validb ? loc2 : 0.f;
  // fp32 q: fold kgroups across halves, then mask rows to this half's sample
  float q2 = q + shfl_x32(q);
  float qv = validb ? q2 : 0.f;

  asm volatile("s_waitcnt lgkmcnt(0)" ::: "memory");  // dots/P visible in-wave

  // ---- pair phase: lanes 0-31 do b0's 196 pairs, lanes 32-63 do b1's ----
  const int half = lane >> 5;
  const int hl = lane & 31;
  const float* dp = dots_l[wid][half];
  const float* Pp = P_l[wid][half];
  float S = 0.f, Gc = 0.f;
#pragma unroll
  for (int r = 0; r < 7; ++r) {
    const int tt = r * 28 + hl;
    if (hl < 28) {
      const int p = (tt * 2341) >> 15;  // tt/14, exact for tt<196
      const int n = tt - p * 14;
      const float Ppv = Pp[p], Pnv = Pp[n];
      S += Ppv * (1.f - Pnv) * softplus_f(dp[n] - dp[p]);
      Gc = fmaf(Ppv * Pnv, G_l[tt], Gc);
    }
  }
  float npv = (hl < 14) ? Pp[hl] : 0.f;
  float w2v = (hl < 14) ? Pp[hl] * G_l[hl * 15] : 0.f;  // P[c]*G[c][c]

  // ---- six half-reductions: lane31 = b0 totals, lane63 = b1 totals ----
  S = hsum32(S);
  Gc = hsum32(Gc);
  s2v = hsum32(s2v);
  qv = hsum32(qv);
  npv = hsum32(npv);
  w2v = hsum32(w2v);

  float loss = 0.f;
  if ((lane & 31) == 31) {
    const float npos = npv;
    const float base = S / npos;  // nneg>=1 guaranteed (y[:,-1]=0)
    const float tv =
        (npos > 1.5f) ? (w2v - Gc / npos) / (npos - 1.f) : 0.f;
    // l1 = sum_e sig2 (var >= 0 so |.| drops) = (sum u^2 - (1/8) sum_e t^2)/7
    const float l1 = (qv - s2v * 0.125f) * (1.f / 7.f);
    loss = 1.4f * (1.f + tv) * base + 0.6f * l1;  // 2*((1-b)(1+tv)base + b*l1)
  }
  loss += shfl_x32(loss);  // lane31 = b0+b1
  if (lane == 31) atomicAdd(&slots[blockIdx.x & (NSLOTS - 1)], loss);
}

// ---- finalize (1 wave): sum the 256 slots -> out[0] ----
__global__ void MID_LOSS_fin(const float* __restrict__ wsf,
                             float* __restrict__ out) {
  const int tid = threadIdx.x;  // 64 threads
  float s = wsf[tid] + wsf[tid + 64] + wsf[tid + 128] + wsf[tid + 192];
  s = wsum64(s);
  if (tid == 63) out[0] = s * (1.f / (float)BATCH);
}

extern "C" void kernel_launch(void* const* d_in, const int* in_sizes, int n_in,
                              void* d_out, int out_size, void* d_ws, size_t ws_size,
                              hipStream_t stream) {
  const float* x = (const float*)d_in[0];
  const int* y = (const int*)d_in[1];
  const float* w = (const float*)d_in[2];
  float* out = (float*)d_out;
  float* wsf = (float*)d_ws;

  MID_LOSS_prep<<<1, 256, 0, stream>>>(w, wsf);
  MID_LOSS_main<<<BATCH / 8, 256, 0, stream>>>(x, y, wsf, wsf);
  MID_LOSS_fin<<<1, 64, 0, stream>>>(wsf, out);
}

// Round 6
// 212.096 us; speedup vs baseline: 1.2092x; 1.0222x over previous
//
#include <hip/hip_runtime.h>
#include <math.h>

#define E_LEN 512
#define C_CLS 14
#define BATCH 8192
#define NSLOTS 256
#define WS_G 256    // Gram offset in ws (floats)
#define WS_WB 464   // packed bf16 w offset in ws (dwords)
#define WB_ROW 260  // dwords per wB row
#define NCH 16      // K chunks of 32 e
#define XKG 72      // kg-group stride in xs (64 data + 8 pad dwords)
#define XSLOT 288   // per-sample slot stride (4 kg-groups)
#define XBUF 576    // per-buffer stride (2 slots)
#define XW 1152     // per-wave xs dwords (2 buffers)

typedef float v4f __attribute__((ext_vector_type(4)));
typedef short s8v __attribute__((ext_vector_type(8)));  // 8 bf16 (4 VGPRs)
union APk { int i[4]; s8v s; };

// f32 pair -> packed bf16 (RNE), gfx950 VOP3
#define CVT_PK_BF16(d, a, b) \
  asm("v_cvt_pk_bf16_f32 %0, %1, %2" : "=v"(d) : "v"(a), "v"(b))

// async global->LDS DMA: each lane 4 B from its gptr -> ldsbase + lane*4
__device__ __forceinline__ void dma4(const float* gp, float* lp) {
  __builtin_amdgcn_global_load_lds(
      (const __attribute__((address_space(1))) void*)gp,
      (__attribute__((address_space(3))) void*)lp, 4, 0, 0);
}

// ---- cross-lane helpers (VALU-pipe DPP) ----
template<int CTRL>
__device__ __forceinline__ float dpp_mov_f(float v) {
  return __int_as_float(__builtin_amdgcn_update_dpp(
      0, __float_as_int(v), CTRL, 0xF, 0xF, false));
}
__device__ __forceinline__ float sum16(float v) {  // row16 sum (ror 8,4,2,1)
  v += dpp_mov_f<0x128>(v);
  v += dpp_mov_f<0x124>(v);
  v += dpp_mov_f<0x122>(v);
  v += dpp_mov_f<0x121>(v);
  return v;
}
// lane31 = sum(lanes 0..31), lane63 = sum(lanes 32..63)
__device__ __forceinline__ float hsum32(float v) {
  v = sum16(v);
  v += dpp_mov_f<0x142>(v);  // row_bcast15
  return v;
}
__device__ __forceinline__ float wsum64(float v) {
  v = sum16(v);
  v += dpp_mov_f<0x142>(v);
  v += dpp_mov_f<0x143>(v);
  return v;
}
template<int PAT>
__device__ __forceinline__ float swz_f(float v) {  // 32-lane-group swizzle
  return __int_as_float(__builtin_amdgcn_ds_swizzle(__float_as_int(v), PAT));
}
__device__ __forceinline__ float shfl_x32(float v) {
  return __shfl_xor(v, 32, 64);
}
__device__ __forceinline__ float softplus_f(float v) {
  return fmaxf(v, 0.f) + __logf(1.f + __expf(-fabsf(v)));
}

// ---- prep (1 block): zero slots, Gram G=w^T w (fp32), pack w -> bf16 rows ----
__global__ void MID_LOSS_prep(const float* __restrict__ w,
                              float* __restrict__ wsf) {
  __shared__ float wl[E_LEN * C_CLS];
  const int tid = threadIdx.x;
#pragma unroll
  for (int i = 0; i < 7; ++i)
    ((float4*)wl)[tid + i * 256] = ((const float4*)w)[tid + i * 256];
  wsf[tid] = 0.f;  // slots
  __syncthreads();
  if (tid < 196) {
    const int p = tid / 14, n = tid - p * 14;
    float g = 0.f;
    for (int e = 0; e < E_LEN; ++e)
      g = fmaf(wl[e * 14 + p], wl[e * 14 + n], g);
    wsf[WS_G + tid] = g;
  }
  // wB[c][e] bf16, c padded to 16 (zeros), row stride WB_ROW dwords
  unsigned int* wsu = (unsigned int*)wsf;
  for (int i = tid; i < 4096; i += 256) {
    const int c = i >> 8;        // 0..15
    const int ep = i & 255;      // e-pair
    const int e = ep * 2;
    const float v0 = (c < 14) ? wl[e * 14 + c] : 0.f;
    const float v1 = (c < 14) ? wl[(e + 1) * 14 + c] : 0.f;
    int d;
    CVT_PK_BF16(d, v0, v1);
    wsu[WS_WB + c * WB_ROW + ep] = (unsigned int)d;
  }
}

// ---- main: 1 block = 8 samples; wave-private DMA staging, zero K-loop
//      barriers, fine-grained vmcnt pipeline, MFMA core ----
__global__ __launch_bounds__(256, 4)
void MID_LOSS_main(const float* __restrict__ x, const int* __restrict__ y,
                   const float* __restrict__ wsf, float* __restrict__ slots) {
  __shared__ unsigned int wB_l[16 * WB_ROW];  // 16.6 KB bf16 w
  __shared__ float G_l[196];
  __shared__ alignas(16) float xs[4 * XW];    // 18 KB wave-private x stage
  __shared__ float dots_l[4][2][16];
  __shared__ float P_l[4][2][16];

  const int tid = threadIdx.x;
  const int lane = tid & 63;
  const int wid = tid >> 6;
  const unsigned int* wsu = (const unsigned int*)wsf;

  // stage packed w + Gram once per block (only cross-wave LDS -> one barrier)
  for (int i = tid; i < 16 * WB_ROW; i += 256) wB_l[i] = wsu[WS_WB + i];
  if (tid < 196) G_l[tid] = wsf[WS_G + tid];
  __syncthreads();

  // fragment geometry: A row = (sample, m), k-slice kg = lane>>4
  const int row = lane & 15;
  const int kg = lane >> 4;
  const int m = row & 7;
  const int b0 = blockIdx.x * 8 + wid * 2;  // this wave's 2 samples
  const float* xg = x + (size_t)b0 * 4096;  // sample b0 base
  float* xw = xs + wid * XW;                // this wave's LDS region
  const float* xr = xw + (row >> 3) * XSLOT + kg * XKG + m;  // read base
  const unsigned int* wrow = wB_l + row * WB_ROW;

  // prime the 2-chunk-deep DMA pipeline (chunks 0,1)
#pragma unroll
  for (int c = 0; c < 2; ++c)
#pragma unroll
    for (int sl = 0; sl < 2; ++sl)
#pragma unroll
      for (int kk = 0; kk < 4; ++kk)
        dma4(xg + sl * 4096 + c * 256 + kk * 64 + lane,
             xw + c * XBUF + sl * XSLOT + kk * XKG);

  v4f acc = {0.f, 0.f, 0.f, 0.f};   // dot C-tile
  v4f acc2 = {0.f, 0.f, 0.f, 0.f};  // Gram C-tile (A*A^T)
  float q = 0.f;                    // fp32 sum u^2 (this lane's slice)

#pragma unroll
  for (int ch = 0; ch < NCH; ++ch) {
    const int buf = ch & 1;
    // wait for chunk ch's 8 DMAs (oldest); keep chunk ch+1's in flight
    if (ch == NCH - 1)
      asm volatile("s_waitcnt vmcnt(0)" ::: "memory");
    else
      asm volatile("s_waitcnt vmcnt(8)" ::: "memory");

    float u[8];
    const float* xb = xr + buf * XBUF;
#pragma unroll
    for (int j = 0; j < 8; ++j) u[j] = xb[j * 8];
    const s8v bfrag = *(const s8v*)(wrow + ch * 16 + kg * 4);
#pragma unroll
    for (int j = 0; j < 8; ++j) q = fmaf(u[j], u[j], q);
    APk a;
#pragma unroll
    for (int jj = 0; jj < 4; ++jj)
      CVT_PK_BF16(a.i[jj], u[2 * jj], u[2 * jj + 1]);

    // refill this buffer with chunk ch+2 (in-wave WAR: drain ds_reads first)
    if (ch < NCH - 2) {
      asm volatile("s_waitcnt lgkmcnt(0)" ::: "memory");
#pragma unroll
      for (int sl = 0; sl < 2; ++sl)
#pragma unroll
        for (int kk = 0; kk < 4; ++kk)
          dma4(xg + sl * 4096 + (ch + 2) * 256 + kk * 64 + lane,
               xw + buf * XBUF + sl * XSLOT + kk * XKG);
    }

    acc = __builtin_amdgcn_mfma_f32_16x16x32_bf16(a.s, bfrag, acc, 0, 0, 0);
    acc2 = __builtin_amdgcn_mfma_f32_16x16x32_bf16(a.s, a.s, acc2, 0, 0, 0);
  }

  // ---- stage P mask for the wave's 2 samples (same-wave, no barrier) ----
  if (lane < 28) {
    const int s = (lane >= 14) ? 1 : 0;
    P_l[wid][s][lane - s * 14] = (y[b0 * 14 + lane] == 1) ? 1.f : 0.f;
  }

  // ---- dot tail: max over m (C layout: col=lane&15, row=kg*4+reg) ----
  float dmax = fmaxf(fmaxf(acc[0], acc[1]), fmaxf(acc[2], acc[3]));
  dmax = fmaxf(dmax, swz_f<0x401F>(dmax));  // xor16: combine kg pairs
  if ((lane & 16) == 0 && (lane & 15) < 14)
    dots_l[wid][lane >> 5][lane & 15] = dmax;

  // ---- Gram tail: per-sample 8x8 block sum (for l1) ----
  const float loc2 = acc2[0] + acc2[1] + acc2[2] + acc2[3];
  const bool validb = (((lane & 15) < 8) == (lane < 32));
  float s2v = validb ? loc2 : 0.f;
  float q2 = q + shfl_x32(q);
  float qv = validb ? q2 : 0.f;

  asm volatile("s_waitcnt lgkmcnt(0)" ::: "memory");  // dots/P visible in-wave

  // ---- pair phase: lanes 0-31 do b0's 196 pairs, lanes 32-63 do b1's ----
  const int half = lane >> 5;
  const int hl = lane & 31;
  const float* dp = dots_l[wid][half];
  const float* Pp = P_l[wid][half];
  float S = 0.f, Gc = 0.f;
#pragma unroll
  for (int r = 0; r < 7; ++r) {
    const int tt = r * 28 + hl;
    if (hl < 28) {
      const int p = (tt * 2341) >> 15;  // tt/14, exact for tt<196
      const int n = tt - p * 14;
      const float Ppv = Pp[p], Pnv = Pp[n];
      S += Ppv * (1.f - Pnv) * softplus_f(dp[n] - dp[p]);
      Gc = fmaf(Ppv * Pnv, G_l[tt], Gc);
    }
  }
  float npv = (hl < 14) ? Pp[hl] : 0.f;
  float w2v = (hl < 14) ? Pp[hl] * G_l[hl * 15] : 0.f;  // P[c]*G[c][c]

  // ---- six half-reductions: lane31 = b0 totals, lane63 = b1 totals ----
  S = hsum32(S);
  Gc = hsum32(Gc);
  s2v = hsum32(s2v);
  qv = hsum32(qv);
  npv = hsum32(npv);
  w2v = hsum32(w2v);

  float loss = 0.f;
  if ((lane & 31) == 31) {
    const float npos = npv;
    const float base = S / npos;  // nneg>=1 guaranteed (y[:,-1]=0)
    const float tv =
        (npos > 1.5f) ? (w2v - Gc / npos) / (npos - 1.f) : 0.f;
    // l1 = sum_e sig2 (var >= 0) = (sum u^2 - (1/8) sum_e t^2)/7
    const float l1 = (qv - s2v * 0.125f) * (1.f / 7.f);
    loss = 1.4f * (1.f + tv) * base + 0.6f * l1;  // 2*((1-b)(1+tv)base + b*l1)
  }
  loss += shfl_x32(loss);  // lane31 = b0+b1
  if (lane == 31) atomicAdd(&slots[blockIdx.x & (NSLOTS - 1)], loss);
}

// ---- finalize (1 wave): sum the 256 slots -> out[0] ----
__global__ void MID_LOSS_fin(const float* __restrict__ wsf,
                             float* __restrict__ out) {
  const int tid = threadIdx.x;  // 64 threads
  float s = wsf[tid] + wsf[tid + 64] + wsf[tid + 128] + wsf[tid + 192];
  s = wsum64(s);
  if (tid == 63) out[0] = s * (1.f / (float)BATCH);
}

extern "C" void kernel_launch(void* const* d_in, const int* in_sizes, int n_in,
                              void* d_out, int out_size, void* d_ws, size_t ws_size,
                              hipStream_t stream) {
  const float* x = (const float*)d_in[0];
  const int* y = (const int*)d_in[1];
  const float* w = (const float*)d_in[2];
  float* out = (float*)d_out;
  float* wsf = (float*)d_ws;

  MID_LOSS_prep<<<1, 256, 0, stream>>>(w, wsf);
  MID_LOSS_main<<<BATCH / 8, 256, 0, stream>>>(x, y, wsf, wsf);
  MID_LOSS_fin<<<1, 64, 0, stream>>>(wsf, out);
}